// Round 3
// baseline (178.148 us; speedup 1.0000x reference)
//
#include <hip/hip_runtime.h>

#define NTOK 16384
#define DIM  512
#define NEXP 8
#define TOPK 2
#define NCAP NTOK            // per-expert segment capacity
#define NITEMS (NTOK*TOPK)

#define BM 128
#define BN 128
#define BK 32                // UNPADDED: required for global_load_lds lane-contiguous dest

typedef __bf16 bf16x8 __attribute__((ext_vector_type(8)));
typedef __bf16 bf16x4 __attribute__((ext_vector_type(4)));
typedef float  f32x4  __attribute__((ext_vector_type(4)));

// async global->LDS 16B per lane. LDS dest MUST be wave-uniform-base + lane*16.
__device__ __forceinline__ void async_cp16(const void* g, void* l) {
    __builtin_amdgcn_global_load_lds((const __attribute__((address_space(1))) void*)g,
                                     (__attribute__((address_space(3))) void*)l, 16, 0, 0);
}

// ---------------- K1: fused prep ----------------
// blocks [0,2048)    : W [E][k][o] f32 -> Wt tiled [e][kt][o][32] bf16 (transpose+convert)
// blocks [2048,2304) : x f32 -> xb bf16
// blocks [2304,2432) : routing scatter (counting sort into fixed segments)
// blocks [2432,2944) : zero out (atomic accumulation target) + loss slot
__global__ __launch_bounds__(256) void k_prep(const float* __restrict__ W,
                                              __bf16* __restrict__ Wt,
                                              const float* __restrict__ x,
                                              __bf16* __restrict__ xb,
                                              const int* __restrict__ indices,
                                              const float* __restrict__ probs,
                                              int* __restrict__ cursor,
                                              int* __restrict__ slot_arr,
                                              float* __restrict__ wgt_arr,
                                              float* __restrict__ out) {
    int b = blockIdx.x, tid = threadIdx.x;
    if (b < 2048) {
        __shared__ __bf16 tile[32][34];             // +2 pad breaks transpose bank conflicts
        int e = b >> 8, rem = b & 255;
        int o0 = (rem >> 4) * 32, k0 = (rem & 15) * 32;
        const float* Wsrc = W + ((size_t)e * DIM + k0) * DIM + o0;
        for (int i = tid; i < 1024; i += 256) {
            int kk = i >> 5, oo = i & 31;           // consecutive tid -> consecutive oo: coalesced
            tile[oo][kk] = (__bf16)Wsrc[(size_t)kk * DIM + oo];
        }
        __syncthreads();
        __bf16* dst = Wt + ((size_t)(e * 16 + (k0 >> 5)) * DIM + o0) * 32;
        for (int i = tid; i < 1024; i += 256) {
            int oo = i >> 5, kk = i & 31;           // row o0+oo, 32 k-elems contiguous
            dst[oo * 32 + kk] = tile[oo][kk];
        }
    } else if (b < 2304) {
        int base = (b - 2048) * 256 + tid;          // 2,097,152 float4 over 256 blocks
        const float4* src = (const float4*)x;
        #pragma unroll
        for (int it = 0; it < 32; ++it) {
            int i = base + it * 65536;
            float4 v = src[i];
            bf16x4 h; h[0] = (__bf16)v.x; h[1] = (__bf16)v.y; h[2] = (__bf16)v.z; h[3] = (__bf16)v.w;
            *(bf16x4*)&xb[(size_t)i * 4] = h;
        }
    } else if (b < 2432) {
        __shared__ int lcnt[NEXP], lbase[NEXP];
        int t = (b - 2304) * 256 + tid;             // item id = n*TOPK + k
        if (tid < NEXP) lcnt[tid] = 0;
        __syncthreads();
        int   e = indices[t];
        float p = probs[t];
        int lr = atomicAdd(&lcnt[e], 1);
        __syncthreads();
        if (tid < NEXP) lbase[tid] = atomicAdd(&cursor[tid], lcnt[tid]);
        __syncthreads();
        int pos = e * NCAP + lbase[e] + lr;
        slot_arr[pos] = t;
        wgt_arr[pos]  = p;
    } else {
        int idx = (b - 2432) * 256 + tid;           // 512 blocks x 256 thr x 16 float4 = 33.55 MB
        float4* o4 = (float4*)out;
        float4 z = {0.f, 0.f, 0.f, 0.f};
        #pragma unroll
        for (int it = 0; it < 16; ++it) o4[idx + it * 131072] = z;
        if (b == 2432 && tid == 0) out[NTOK * DIM] = 0.0f;   // total_loss
    }
}

// ---------------- K2: grouped GEMM, atomic accumulate into out ----------------
// grid = 264 m-tile-slots x 4 n-tiles = 1056 blocks, all active (prefix over cnt).
// XCD swizzle: m_slot = (p>>5)*8 + (p&7), nt = (p>>3)&3 -> 4 n-tiles of one m-tile share an XCD.
__global__ __launch_bounds__(256) void k_gemm(const __bf16* __restrict__ xb,
                                              const __bf16* __restrict__ Wt,
                                              const float* __restrict__ bias,
                                              const int* __restrict__ slot_arr,
                                              const float* __restrict__ wgt_arr,
                                              const int* __restrict__ cnt,
                                              float* __restrict__ out) {
    int p = blockIdx.x;
    int m_slot = (p >> 5) * 8 + (p & 7);
    int nt = (p >> 3) & 3;
    int e = -1, m_t = 0, count = 0, total = 0;
    #pragma unroll
    for (int i = 0; i < NEXP; ++i) {
        int c = cnt[i];
        int t = (c + BM - 1) >> 7;                  // ceil(count/128) tiles for expert i
        if (e < 0 && m_slot < total + t) { e = i; m_t = m_slot - total; count = c; }
        total += t;
    }
    if (e < 0) return;                              // padding slots (total <= 264 always)
    int m0 = m_t * BM, n0 = nt * BN, tid = threadIdx.x;

    __shared__ __attribute__((aligned(16))) __bf16 sA[BM * BK];
    __shared__ __attribute__((aligned(16))) __bf16 sB[BN * BK];
    __shared__ int   sslot[BM];
    __shared__ float swgt[BM];

    if (tid < BM) {
        int g = m0 + tid;
        int s = 0; float w = 0.f;
        if (g < count) { s = slot_arr[e * NCAP + g]; w = wgt_arr[e * NCAP + g]; }
        sslot[tid] = s;                             // invalid rows alias token 0 (loads safe, store skipped)
        swgt[tid]  = w;
    }
    __syncthreads();

    int wid  = tid >> 6, lane = tid & 63;
    int quad = lane >> 4, rr  = lane & 15;
    int wm = (wid >> 1) * 64, wn = (wid & 1) * 64;  // 2x2 waves over 128x128

    // A staging duty (fixed per thread): chunks c and c+256; row=c>>2, kc=(c&3)*8.
    // LDS dest byte = c*16 -> wave-uniform base + lane*16 (lane-contiguous, unpadded) ✓
    int rA0 = tid >> 2,          kcA0 = (tid & 3) << 3;
    int rA1 = (tid + 256) >> 2,  kcA1 = (tid & 3) << 3;
    const __bf16* gA0 = xb + (size_t)(sslot[rA0] >> 1) * DIM + kcA0;   // token rows hoisted
    const __bf16* gA1 = xb + (size_t)(sslot[rA1] >> 1) * DIM + kcA1;
    // B staging: Wt tiled layout makes each kt-slab (n0-row-block) fully contiguous.
    const __bf16* gB  = Wt + ((size_t)(e * 16) * DIM + n0) * 32 + tid * 8;

    f32x4 acc[4][4] = {};

    for (int kt = 0; kt < DIM / BK; ++kt) {
        async_cp16(gA0 + kt * BK,                (char*)sA + tid * 16);
        async_cp16(gA1 + kt * BK,                (char*)sA + tid * 16 + 4096);
        async_cp16(gB  + (size_t)kt * DIM * 32,  (char*)sB + tid * 16);
        async_cp16(gB  + (size_t)kt * DIM * 32 + 2048, (char*)sB + tid * 16 + 4096);
        __syncthreads();                            // drains vmcnt -> LDS tiles ready
        bf16x8 af[4], bfr[4];
        #pragma unroll
        for (int i = 0; i < 4; ++i)
            af[i] = *(bf16x8*)&sA[(wm + i * 16 + rr) * BK + quad * 8];   // A[m=rr][k=quad*8+j]
        #pragma unroll
        for (int j = 0; j < 4; ++j)
            bfr[j] = *(bf16x8*)&sB[(wn + j * 16 + rr) * BK + quad * 8];  // B[n=rr][k=quad*8+j]
        #pragma unroll
        for (int i = 0; i < 4; ++i)
            #pragma unroll
            for (int j = 0; j < 4; ++j)
                acc[i][j] = __builtin_amdgcn_mfma_f32_16x16x32_bf16(af[i], bfr[j], acc[i][j], 0, 0, 0);
        __syncthreads();
    }

    // epilogue: C/D layout col=lane&15, row=quad*4+reg.  out[tok] += (acc + b)*p  (fp32 atomics)
    float bv[4];
    #pragma unroll
    for (int j = 0; j < 4; ++j) bv[j] = bias[e * DIM + n0 + wn + j * 16 + rr];
    #pragma unroll
    for (int i = 0; i < 4; ++i) {
        #pragma unroll
        for (int reg = 0; reg < 4; ++reg) {
            int row = wm + i * 16 + quad * 4 + reg;
            int g = m0 + row;
            if (g >= count) continue;
            int   tok = sslot[row] >> 1;
            float w   = swgt[row];
            float* dst = out + (size_t)tok * DIM + n0 + wn + rr;
            #pragma unroll
            for (int j = 0; j < 4; ++j)
                atomicAdd(&dst[j * 16], (acc[i][j][reg] + bv[j]) * w);
        }
    }
}

extern "C" void kernel_launch(void* const* d_in, const int* in_sizes, int n_in,
                              void* d_out, int out_size, void* d_ws, size_t ws_size,
                              hipStream_t stream) {
    const float* x    = (const float*)d_in[0];   // [N, D]
    const float* prob = (const float*)d_in[1];   // [N, K]
    const int*   idx  = (const int*)d_in[2];     // [N, K]
    const float* W    = (const float*)d_in[3];   // [E, D, D]
    const float* b    = (const float*)d_in[4];   // [E, D]
    float* out = (float*)d_out;                  // [N*D + 1]

    // workspace:
    //   Wt      : E*D*D bf16 (K-tiled [e][kt][o][32]) =  4,194,304 B
    //   xb      : N*D bf16                            = 16,777,216 B
    //   cursor  : 8 int (256 B reserved)
    //   slot_arr: E*NCAP int                          =    524,288 B
    //   wgt_arr : E*NCAP float                        =    524,288 B    total ~22 MB
    char* ws = (char*)d_ws;
    __bf16* Wt       = (__bf16*)ws;
    __bf16* xb       = (__bf16*)(ws + 4194304);
    int*    cursor   = (int*)   (ws + 4194304 + 16777216);
    int*    slot_arr = (int*)   (ws + 4194304 + 16777216 + 256);
    float*  wgt_arr  = (float*) (ws + 4194304 + 16777216 + 256 + 524288);

    hipMemsetAsync(cursor, 0, NEXP * sizeof(int), stream);
    hipLaunchKernelGGL(k_prep, dim3(2944), dim3(256), 0, stream,
                       W, Wt, x, xb, idx, prob, cursor, slot_arr, wgt_arr, out);
    hipLaunchKernelGGL(k_gemm, dim3(1056), dim3(256), 0, stream,
                       xb, Wt, b, slot_arr, wgt_arr, cursor, out);
}

// Round 5
// 145.540 us; speedup vs baseline: 1.2240x; 1.2240x over previous
//
#include <hip/hip_runtime.h>

#define NTOK 16384
#define DIM  512
#define NEXP 8
#define TOPK 2
#define NCAP NTOK            // per-expert segment capacity
#define NITEMS (NTOK*TOPK)

#define BM 128
#define BN 128
#define BK 32                // UNPADDED: required for global_load_lds lane-contiguous dest

typedef __bf16 bf16x8 __attribute__((ext_vector_type(8)));
typedef __bf16 bf16x4 __attribute__((ext_vector_type(4)));
typedef float  f32x4  __attribute__((ext_vector_type(4)));

// async global->LDS 16B per lane. LDS dest MUST be wave-uniform base + lane*16.
__device__ __forceinline__ void async_cp16(const void* g, void* l) {
    __builtin_amdgcn_global_load_lds((const __attribute__((address_space(1))) void*)g,
                                     (__attribute__((address_space(3))) void*)l, 16, 0, 0);
}

// ---------------- K1: fused prep ----------------
// blocks [0,2048)    : W [E][k][o] f32 -> Wt tiled [e][kt][o][32] bf16 (transpose+convert)
// blocks [2048,2304) : x f32 -> xb bf16
// blocks [2304,2432) : routing scatter (counting sort into fixed segments)
__global__ __launch_bounds__(256) void k_prep(const float* __restrict__ W,
                                              __bf16* __restrict__ Wt,
                                              const float* __restrict__ x,
                                              __bf16* __restrict__ xb,
                                              const int* __restrict__ indices,
                                              const float* __restrict__ probs,
                                              int* __restrict__ cursor,
                                              int* __restrict__ slot_arr,
                                              float* __restrict__ wgt_arr) {
    int b = blockIdx.x, tid = threadIdx.x;
    if (b < 2048) {
        __shared__ __bf16 tile[32][34];             // +2 pad breaks transpose bank conflicts
        int e = b >> 8, rem = b & 255;
        int o0 = (rem >> 4) * 32, k0 = (rem & 15) * 32;
        const float* Wsrc = W + ((size_t)e * DIM + k0) * DIM + o0;
        for (int i = tid; i < 1024; i += 256) {
            int kk = i >> 5, oo = i & 31;           // consecutive tid -> consecutive oo: coalesced
            tile[oo][kk] = (__bf16)Wsrc[(size_t)kk * DIM + oo];
        }
        __syncthreads();
        __bf16* dst = Wt + ((size_t)(e * 16 + (k0 >> 5)) * DIM + o0) * 32;
        for (int i = tid; i < 1024; i += 256) {
            int oo = i >> 5, kk = i & 31;           // row o0+oo, 32 k-elems contiguous
            dst[oo * 32 + kk] = tile[oo][kk];
        }
    } else if (b < 2304) {
        int base = (b - 2048) * 256 + tid;          // 2,097,152 float4 over 256 blocks
        const float4* src = (const float4*)x;
        #pragma unroll
        for (int it = 0; it < 32; ++it) {
            int i = base + it * 65536;
            float4 v = src[i];
            bf16x4 h; h[0] = (__bf16)v.x; h[1] = (__bf16)v.y; h[2] = (__bf16)v.z; h[3] = (__bf16)v.w;
            *(bf16x4*)&xb[(size_t)i * 4] = h;
        }
    } else {
        __shared__ int lcnt[NEXP], lbase[NEXP];
        int t = (b - 2304) * 256 + tid;             // item id = n*TOPK + k
        if (tid < NEXP) lcnt[tid] = 0;
        __syncthreads();
        int   e = indices[t];
        float p = probs[t];
        int lr = atomicAdd(&lcnt[e], 1);
        __syncthreads();
        if (tid < NEXP) lbase[tid] = atomicAdd(&cursor[tid], lcnt[tid]);
        __syncthreads();
        int pos = e * NCAP + lbase[e] + lr;
        slot_arr[pos] = t;
        wgt_arr[pos]  = p;
    }
}

// ---------------- K2: grouped GEMM, double-buffered async staging ----------------
// grid = 1056. XCD pin: r = p&7 -> XCD r (round-robin heuristic); nt = r>>1 fixed per XCD
// => each XCD's L2 holds one 128-col Wt slice per expert (8 x 128KB = 1MB, resident).
// m_slot = (p>>3)*2 + (r&1) walks all 264 m-tile slots.
__global__ __launch_bounds__(256) void k_gemm(const __bf16* __restrict__ xb,
                                              const __bf16* __restrict__ Wt,
                                              const float* __restrict__ bias,
                                              const int* __restrict__ slot_arr,
                                              const float* __restrict__ wgt_arr,
                                              const int* __restrict__ cnt,
                                              __bf16* __restrict__ partial) {
    int p = blockIdx.x;
    int r = p & 7;
    int m_slot = (p >> 3) * 2 + (r & 1);
    int nt = r >> 1;
    int e = -1, m_t = 0, count = 0, total = 0;
    #pragma unroll
    for (int i = 0; i < NEXP; ++i) {
        int c = cnt[i];
        int t = (c + BM - 1) >> 7;                  // ceil(count/128) m-tiles for expert i
        if (e < 0 && m_slot < total + t) { e = i; m_t = m_slot - total; count = c; }
        total += t;
    }
    if (e < 0) return;                              // padding slots (total <= 264)
    int m0 = m_t * BM, n0 = nt * BN, tid = threadIdx.x;

    // double-buffered staging: A buffers @0/8K, B buffers @16K/24K
    __shared__ __attribute__((aligned(16))) char smem[32768];
    __shared__ int   sslot[BM];
    __shared__ float swgt[BM];

    if (tid < BM) {
        int g = m0 + tid;
        int s = 0; float w = 0.f;
        if (g < count) { s = slot_arr[e * NCAP + g]; w = wgt_arr[e * NCAP + g]; }
        sslot[tid] = s;                             // invalid rows alias token 0 (loads safe, store skipped)
        swgt[tid]  = w;
    }
    __syncthreads();

    int wid  = tid >> 6, lane = tid & 63;
    int quad = lane >> 4, rr  = lane & 15;
    int wm = (wid >> 1) * 64, wn = (wid & 1) * 64;  // 2x2 waves over 128x128

    // A staging duty: chunks tid and tid+256; row=c>>2, kc=(c&3)*8; LDS dest = c*16 bytes
    int rA0 = tid >> 2, kcA = (tid & 3) << 3;
    int rA1 = rA0 + 64;
    const __bf16* gA0 = xb + (size_t)(sslot[rA0] >> 1) * DIM + kcA;
    const __bf16* gA1 = xb + (size_t)(sslot[rA1] >> 1) * DIM + kcA;
    // B staging: tiled Wt makes each kt-slab contiguous (8KB)
    const __bf16* gB  = Wt + ((size_t)(e * 16) * DIM + n0) * 32 + tid * 8;

    f32x4 acc[4][4] = {};

    // preload kt=0 into buffer 0
    async_cp16(gA0,        smem + tid * 16);
    async_cp16(gA1,        smem + tid * 16 + 4096);
    async_cp16(gB,         smem + 16384 + tid * 16);
    async_cp16(gB + 2048,  smem + 16384 + tid * 16 + 4096);

    for (int kt = 0; kt < DIM / BK; ++kt) {
        int cur = kt & 1;
        __syncthreads();                            // drains vmcnt(0): buf[cur] tiles are ready
        if (kt < DIM / BK - 1) {                    // prefetch kt+1 into the other buffer;
            int k1 = (kt + 1) * BK;                 // it stays in flight through the MFMA phase
            const __bf16* gb = gB + (size_t)(kt + 1) * DIM * 32;
            char* dA = smem + (cur ^ 1) * 8192;
            char* dB = smem + 16384 + (cur ^ 1) * 8192;
            async_cp16(gA0 + k1,   dA + tid * 16);
            async_cp16(gA1 + k1,   dA + tid * 16 + 4096);
            async_cp16(gb,         dB + tid * 16);
            async_cp16(gb + 2048,  dB + tid * 16 + 4096);
        }
        const __bf16* sA = (const __bf16*)(smem + cur * 8192);
        const __bf16* sB = (const __bf16*)(smem + 16384 + cur * 8192);
        bf16x8 af[4], bfr[4];
        #pragma unroll
        for (int i = 0; i < 4; ++i)
            af[i] = *(bf16x8*)&sA[(wm + i * 16 + rr) * BK + quad * 8];   // A[m=rr][k=quad*8+j]
        #pragma unroll
        for (int j = 0; j < 4; ++j)
            bfr[j] = *(bf16x8*)&sB[(wn + j * 16 + rr) * BK + quad * 8];  // B[n=rr][k=quad*8+j]
        #pragma unroll
        for (int i = 0; i < 4; ++i)
            #pragma unroll
            for (int j = 0; j < 4; ++j)
                acc[i][j] = __builtin_amdgcn_mfma_f32_16x16x32_bf16(af[i], bfr[j], acc[i][j], 0, 0, 0);
    }

    // epilogue: C/D layout col=lane&15, row=quad*4+reg.  partial[slot][col] = bf16((acc+b)*p)
    float bv[4];
    #pragma unroll
    for (int j = 0; j < 4; ++j) bv[j] = bias[e * DIM + n0 + wn + j * 16 + rr];
    #pragma unroll
    for (int i = 0; i < 4; ++i) {
        #pragma unroll
        for (int reg = 0; reg < 4; ++reg) {
            int row = wm + i * 16 + quad * 4 + reg;
            int g = m0 + row;
            if (g >= count) continue;
            int   s = sslot[row];
            float w = swgt[row];
            __bf16* dst = partial + (size_t)s * DIM + n0 + wn + rr;
            #pragma unroll
            for (int j = 0; j < 4; ++j)
                dst[j * 16] = (__bf16)((acc[i][j][reg] + bv[j]) * w);
        }
    }
}

// ---------------- K3: combine the two bf16 slots per token -> fp32 out + loss ----------------
__global__ __launch_bounds__(256) void k_combine(const __bf16* __restrict__ partial,
                                                 float* __restrict__ out) {
    int t = blockIdx.x * blockDim.x + threadIdx.x;
    const int total8 = NTOK * DIM / 8;              // 1,048,576 chunks of 8
    for (int i = t; i < total8; i += gridDim.x * blockDim.x) {
        int n  = i >> 6;                            // 64 bf16x8-chunks per D-row
        int d8 = (i & 63) << 3;
        bf16x8 a = *(const bf16x8*)(partial + ((size_t)(2 * n)     * DIM) + d8);
        bf16x8 c = *(const bf16x8*)(partial + ((size_t)(2 * n + 1) * DIM) + d8);
        float4 lo, hi;
        lo.x = (float)a[0] + (float)c[0]; lo.y = (float)a[1] + (float)c[1];
        lo.z = (float)a[2] + (float)c[2]; lo.w = (float)a[3] + (float)c[3];
        hi.x = (float)a[4] + (float)c[4]; hi.y = (float)a[5] + (float)c[5];
        hi.z = (float)a[6] + (float)c[6]; hi.w = (float)a[7] + (float)c[7];
        float* o = out + (size_t)n * DIM + d8;
        *(float4*)o       = lo;
        *(float4*)(o + 4) = hi;
    }
    if (t == 0) out[NTOK * DIM] = 0.0f;             // total_loss
}

extern "C" void kernel_launch(void* const* d_in, const int* in_sizes, int n_in,
                              void* d_out, int out_size, void* d_ws, size_t ws_size,
                              hipStream_t stream) {
    const float* x    = (const float*)d_in[0];   // [N, D]
    const float* prob = (const float*)d_in[1];   // [N, K]
    const int*   idx  = (const int*)d_in[2];     // [N, K]
    const float* W    = (const float*)d_in[3];   // [E, D, D]
    const float* b    = (const float*)d_in[4];   // [E, D]
    float* out = (float*)d_out;                  // [N*D + 1]

    // workspace:
    //   Wt      : E*D*D bf16 (K-tiled [e][kt][o][32]) =  4,194,304 B
    //   xb      : N*D bf16                            = 16,777,216 B
    //   cursor  : 8 int (256 B reserved)
    //   slot_arr: E*NCAP int                          =    524,288 B
    //   wgt_arr : E*NCAP float                        =    524,288 B
    //   partial : N*K*D bf16                          = 33,554,432 B   total ~55.6 MB
    char* ws = (char*)d_ws;
    __bf16* Wt       = (__bf16*)ws;
    __bf16* xb       = (__bf16*)(ws + 4194304);
    int*    cursor   = (int*)   (ws + 4194304 + 16777216);
    int*    slot_arr = (int*)   (ws + 4194304 + 16777216 + 256);
    float*  wgt_arr  = (float*) (ws + 4194304 + 16777216 + 256 + 524288);
    __bf16* partial  = (__bf16*)(ws + 4194304 + 16777216 + 256 + 2 * 524288);

    (void)hipMemsetAsync(cursor, 0, NEXP * sizeof(int), stream);
    hipLaunchKernelGGL(k_prep,    dim3(2432), dim3(256), 0, stream,
                       W, Wt, x, xb, idx, prob, cursor, slot_arr, wgt_arr);
    hipLaunchKernelGGL(k_gemm,    dim3(1056), dim3(256), 0, stream,
                       xb, Wt, b, slot_arr, wgt_arr, cursor, partial);
    hipLaunchKernelGGL(k_combine, dim3(2048), dim3(256), 0, stream, partial, out);
}